// Round 12
// baseline (125.004 us; speedup 1.0000x reference)
//
#include <hip/hip_runtime.h>
#include <stdint.h>

// int4 grouped-quant GEMM: out[64][28672] = x[64][8192] . W^T + bias
// W packed [N][K/2] int32, one byte/int32 = 2 nibbles (low = even k), zp = 8,
// per-128-k scales. fp16 ref -> harness gives x/scales/bias/out as FP32.
// Round-12: R11 (kstep-split waves, X-in-regs, lean LDS) + DISTANCE-2 W
// prefetch: triple-buffer W (rotating pointers), per-iter order
// [consume X(g); issue X(g+1); barrier; stage W(g+2); vmcnt(12); barrier]
// so W(g+1) stays in flight across both barriers and W(g) gets two full
// iteration-periods of latency cover (R11 was depth-1: period ~ latency +
// compute ~ 2000 cy; target ~ 1100 cy).

typedef __attribute__((ext_vector_type(8))) short     short8;
typedef __attribute__((ext_vector_type(4))) float     f32x4;
typedef __attribute__((ext_vector_type(4))) int       i32x4;
typedef __attribute__((ext_vector_type(2))) _Float16  f16x2;
typedef __attribute__((ext_vector_type(8))) _Float16  f16x8;

// async global->LDS, 16 B/lane. LDS dest = wave-uniform base + lane*16 (HW);
// global source is PER-LANE -> swizzle via pre-swizzled source (m173).
static __device__ __forceinline__ void gload_lds16(const void* gp, void* lp) {
    __builtin_amdgcn_global_load_lds(
        (const __attribute__((address_space(1))) unsigned int*)gp,
        (__attribute__((address_space(3))) unsigned int*)lp, 16, 0, 0);
}

// int4 pair -> fp16 pair: u = 0x6400|nib (fp16 1024+v, exact), (u-1032) exact
// in f16 (= v-8), then *s (single rounding - matches reference fp16 mul).
static __device__ __forceinline__ f16x8 dequant(const i32x4& w, f16x2 s2) {
    const f16x2 c1032 = {(_Float16)1032.0f, (_Float16)1032.0f};
    union { unsigned u[4]; f16x8 v; } r;
    #pragma unroll
    for (int j = 0; j < 4; ++j) {
        unsigned v = (unsigned)w[j];
        unsigned u = ((v & 0xFu) | 0x64006400u) | ((v << 12) & 0xF0000u);
        f16x2 h = __builtin_bit_cast(f16x2, u);
        h = (h - c1032) * s2;
        r.u[j] = __builtin_bit_cast(unsigned, h);
    }
    return r.v;
}

// x fp32 [64][K] -> fp16 (lossless) in A-fragment order: xf[g][st][mt][lane][8]
__global__ __launch_bounds__(256)
void xpack_kernel(const float* __restrict__ x, unsigned short* __restrict__ xf, int K) {
    int c    = blockIdx.x * 256 + threadIdx.x;
    int g    = c >> 10;
    int st   = (c >> 8) & 3;
    int mt   = (c >> 6) & 3;
    int lane = c & 63;
    int quad = lane >> 4, l15 = lane & 15;
    const float* p = x + (size_t)(l15 + mt * 16) * K + g * 128 + st * 32 + quad * 8;
    f32x4 lo = *(const f32x4*)p;
    f32x4 hi = *(const f32x4*)(p + 4);
    f16x8 r = { (_Float16)lo[0], (_Float16)lo[1], (_Float16)lo[2], (_Float16)lo[3],
                (_Float16)hi[0], (_Float16)hi[1], (_Float16)hi[2], (_Float16)hi[3] };
    *(short8*)(xf + (size_t)c * 8) = __builtin_bit_cast(short8, r);
}

__global__ __launch_bounds__(256, 2)
void int4mm_kernel(const unsigned short* __restrict__ xf,  // fp16 frag-ordered x
                   const int*   __restrict__ wp,           // [N][K/2]
                   const float* __restrict__ sc,           // [N][ng]
                   const float* __restrict__ bias,         // [N]
                   float*       __restrict__ out,          // [64][N]
                   int K, int N)
{
    __shared__ char lds[65536];              // 48 KB W triple-buf | 16 KB scales
    char* w0 = lds;                          // W(g)   (read this iter)
    char* w1 = lds + 16384;                  // W(g+1) (in flight)
    char* w2 = lds + 32768;                  // W(g+2) (stage target)
    float* ldsS = (float*)(lds + 49152);     // [64 g][64 col]

    const int tid  = threadIdx.x;
    const int lane = tid & 63;
    const int wave = tid >> 6;               // kstep owner: k-quarter of each group
    const int quad = lane >> 4;
    const int l15  = lane & 15;
    const int blk64 = blockIdx.x * 64;
    const int ng   = K / 128;                // 64 groups

    const char* wp8 = (const char*)wp;       // one col's W row = 16384 B

    // W stage sources (R7-11-verified involution): instr j of wave w covers
    // local cols w*16+j*4+quad; lane supplies chunk l15^(j*4+quad); LDS slot s
    // of col c ends up holding global chunk s^(c&15).
    unsigned woff[4];
    #pragma unroll
    for (int j = 0; j < 4; ++j) {
        int cloc  = wave * 16 + j * 4 + quad;
        int chunk = l15 ^ (j * 4 + quad);
        woff[j] = ((unsigned)(blk64 + cloc) << 14) + ((unsigned)chunk << 4);
    }

    // B-frag ds_read offsets: col c = nt*16+l15, chunk (wave*4+quad) at slot
    // ((wave*4+quad)^l15) -> beat-optimal (8 beats/instr).
    int rdW[4];
    #pragma unroll
    for (int nt = 0; nt < 4; ++nt)
        rdW[nt] = (nt * 16 + l15) * 256 + (((wave * 4 + quad) ^ l15) << 4);

    // ---- prologue ----
    // scales: ldsS[g][c] = sc[(blk64+c)*ng + g] via 64 B contiguous loads.
    {
        const int c  = tid & 63;
        const int g0 = (tid >> 6) * 16;
        const float* sp = sc + (size_t)(blk64 + c) * ng + g0;
        f32x4 s0 = *(const f32x4*)(sp);
        f32x4 s1 = *(const f32x4*)(sp + 4);
        f32x4 s2 = *(const f32x4*)(sp + 8);
        f32x4 s3 = *(const f32x4*)(sp + 12);
        #pragma unroll
        for (int j = 0; j < 4; ++j) {
            ldsS[(g0 + 0  + j) * 64 + c] = s0[j];
            ldsS[(g0 + 4  + j) * 64 + c] = s1[j];
            ldsS[(g0 + 8  + j) * 64 + c] = s2[j];
            ldsS[(g0 + 12 + j) * 64 + c] = s3[j];
        }
    }
    #pragma unroll
    for (int j = 0; j < 4; ++j)              // stage W(0) -> w0
        gload_lds16(wp8 + woff[j], w0 + (wave * 4 + j) * 1024);
    #pragma unroll
    for (int j = 0; j < 4; ++j)              // stage W(1) -> w1
        gload_lds16(wp8 + woff[j] + 256, w1 + (wave * 4 + j) * 1024);

    const char* xbase = (const char*)xf + wave * 4096 + lane * 16;
    f16x8 xn[4], xc[4];
    #pragma unroll
    for (int mt = 0; mt < 4; ++mt)           // X(0) -> regs
        xn[mt] = *(const f16x8*)(xbase + mt * 1024);

    f32x4 acc[4][4];
    #pragma unroll
    for (int mt = 0; mt < 4; ++mt)
        #pragma unroll
        for (int nt = 0; nt < 4; ++nt)
            acc[mt][nt] = f32x4{0.f, 0.f, 0.f, 0.f};

    __syncthreads();   // prologue drain: scales + W(0) + W(1) + X(0) all landed

    // Main loop. Per-iter VMEM issue order: [X(g+1) x4, W(g+2) x4].
    // vmcnt(12) before barrier-2 leaves the 12 newest {W(g+1), X(g+1), W(g+2)}
    // in flight and forces {X(g), W(g)} (issued >= 1-2 iters ago) complete:
    // W gets TWO full iteration-periods of latency cover.
    #pragma unroll 1
    for (int g = 0; g < ng; ++g) {
        const int gn = (g + 1 < ng) ? g + 1 : ng - 1;   // clamped dead tail
        const int gw = (g + 2 < ng) ? g + 2 : ng - 1;

        #pragma unroll
        for (int mt = 0; mt < 4; ++mt) xc[mt] = xn[mt]; // consume X(g)

        const char* xs = xbase + (size_t)gn * 16384;    // issue X(g+1)
        #pragma unroll
        for (int mt = 0; mt < 4; ++mt)
            xn[mt] = *(const f16x8*)(xs + mt * 1024);

        __builtin_amdgcn_s_barrier();        // iter g-1 readers of w2-target done

        #pragma unroll
        for (int j = 0; j < 4; ++j)          // stage W(g+2) -> w2
            gload_lds16(wp8 + woff[j] + (size_t)gw * 256,
                        w2 + (wave * 4 + j) * 1024);

        asm volatile("s_waitcnt vmcnt(12)" ::: "memory");  // W(g),X(g) done;
        __builtin_amdgcn_s_barrier();                      // W(g+1) untouched
        __builtin_amdgcn_sched_barrier(0);   // keep ds_reads below the sync

        const char* wb = w0;
        i32x4 v0 = *(const i32x4*)(wb + rdW[0]);
        i32x4 v1 = *(const i32x4*)(wb + rdW[1]);
        i32x4 v2 = *(const i32x4*)(wb + rdW[2]);
        i32x4 v3 = *(const i32x4*)(wb + rdW[3]);

        const float* sg = ldsS + g * 64;
        const float sf0 = sg[l15], sf1 = sg[16 + l15];
        const float sf2 = sg[32 + l15], sf3 = sg[48 + l15];

        {
            f16x8 b = dequant(v0, f16x2{(_Float16)sf0, (_Float16)sf0});
            #pragma unroll
            for (int mt = 0; mt < 4; ++mt)
                acc[mt][0] = __builtin_amdgcn_mfma_f32_16x16x32_f16(xc[mt], b, acc[mt][0], 0, 0, 0);
        }
        {
            f16x8 b = dequant(v1, f16x2{(_Float16)sf1, (_Float16)sf1});
            #pragma unroll
            for (int mt = 0; mt < 4; ++mt)
                acc[mt][1] = __builtin_amdgcn_mfma_f32_16x16x32_f16(xc[mt], b, acc[mt][1], 0, 0, 0);
        }
        {
            f16x8 b = dequant(v2, f16x2{(_Float16)sf2, (_Float16)sf2});
            #pragma unroll
            for (int mt = 0; mt < 4; ++mt)
                acc[mt][2] = __builtin_amdgcn_mfma_f32_16x16x32_f16(xc[mt], b, acc[mt][2], 0, 0, 0);
        }
        {
            f16x8 b = dequant(v3, f16x2{(_Float16)sf3, (_Float16)sf3});
            #pragma unroll
            for (int mt = 0; mt < 4; ++mt)
                acc[mt][3] = __builtin_amdgcn_mfma_f32_16x16x32_f16(xc[mt], b, acc[mt][3], 0, 0, 0);
        }

        char* wt = w0; w0 = w1; w1 = w2; w2 = wt;   // rotate W buffers
    }

    // ---- epilogue: cross-wave (kstep) reduce. Wave w owns mt = w. ----
    // Partials: addr(owner o, slot s, nt) = ((o*3+s)*4+nt)*1024 + lane*16 (48 KB).
    __syncthreads();
    #pragma unroll
    for (int o = 0; o < 4; ++o) {
        if (o == wave) continue;             // wave-uniform branch
        const int s = wave - (wave > o ? 1 : 0);
        #pragma unroll
        for (int nt = 0; nt < 4; ++nt)
            *(f32x4*)(lds + (size_t)(((o * 3 + s) * 4 + nt) * 1024) + lane * 16)
                = acc[o][nt];
    }
    __syncthreads();

    f32x4 own[4];
    #pragma unroll
    for (int nt = 0; nt < 4; ++nt) own[nt] = acc[0][nt];
    #pragma unroll
    for (int o = 1; o < 4; ++o)
        if (wave == o) {                     // wave-uniform, compile-time acc idx
            own[0] = acc[o][0]; own[1] = acc[o][1];
            own[2] = acc[o][2]; own[3] = acc[o][3];
        }
    #pragma unroll
    for (int s = 0; s < 3; ++s)
        #pragma unroll
        for (int nt = 0; nt < 4; ++nt)
            own[nt] += *(const f32x4*)(lds + (size_t)(((wave * 3 + s) * 4 + nt) * 1024)
                                       + lane * 16);

    #pragma unroll
    for (int nt = 0; nt < 4; ++nt) {
        const int col = blk64 + nt * 16 + l15;
        const float bv = bias[col];
        #pragma unroll
        for (int r = 0; r < 4; ++r)
            out[(size_t)(wave * 16 + quad * 4 + r) * N + col] = own[nt][r] + bv;
    }
}

extern "C" void kernel_launch(void* const* d_in, const int* in_sizes, int n_in,
                              void* d_out, int out_size, void* d_ws, size_t ws_size,
                              hipStream_t stream)
{
    const float* x    = (const float*)d_in[0];
    const int*   wp   = (const int*)d_in[1];
    const float* sc   = (const float*)d_in[2];
    const float* bias = (const float*)d_in[3];
    float*       out  = (float*)d_out;

    const int N  = in_sizes[3];                       // 28672
    const long long Kh = (long long)in_sizes[1] / N;  // 4096
    const int K  = (int)(2 * Kh);                     // 8192
    const int ng = K / 128;                           // 64

    unsigned short* xf = (unsigned short*)d_ws;       // 1 MB frag-ordered fp16 x

    xpack_kernel<<<(ng * 1024) / 256, 256, 0, stream>>>(x, xf, K);
    int4mm_kernel<<<N / 64, 256, 0, stream>>>(xf, wp, sc, bias, out, K, N);
}